// Round 1
// baseline (1964.420 us; speedup 1.0000x reference)
//
#include <hip/hip_runtime.h>
#include <hip/hip_bf16.h>
#include <math.h>

typedef __attribute__((ext_vector_type(8))) __bf16 bf16x8;
typedef __attribute__((ext_vector_type(8))) short short8;
typedef __attribute__((ext_vector_type(4))) float f32x4;
typedef __attribute__((ext_vector_type(4))) unsigned short ushort4v;

#define AS1 __attribute__((address_space(1)))
#define AS3 __attribute__((address_space(3)))

__device__ __forceinline__ unsigned short f2bf(float f) {
  __hip_bfloat16 h = __float2bfloat16(f);
  return __builtin_bit_cast(unsigned short, h);
}
__device__ __forceinline__ float bf2f(unsigned short s) {
  unsigned int u = ((unsigned int)s) << 16;
  return __builtin_bit_cast(float, u);
}

// ---------- fp32 -> bf16 conversion, 4 elems/thread, grid-stride ----------
__global__ void cvt_f32_bf16(const float4* __restrict__ in,
                             ushort4v* __restrict__ out, size_t n4) {
  size_t i = (size_t)blockIdx.x * blockDim.x + threadIdx.x;
  size_t stride = (size_t)gridDim.x * blockDim.x;
  for (; i < n4; i += stride) {
    float4 v = in[i];
    ushort4v o = { f2bf(v.x), f2bf(v.y), f2bf(v.z), f2bf(v.w) };
    out[i] = o;
  }
}

// ---------- bf16 GEMM: C = A[M,K] * B[N,K]^T (+ bias[n]) ----------
// m97 structure: 128x128 tile, BK=64, 4 waves (2x2), 16x16x32 MFMA,
// global_load_lds width=16, 2-barrier K-loop.
// EPI 0: Cb[m,n] = bf16(gelu_exact(acc + bias[n]))
// EPI 1: Cf[m,n]  = wgt[m*8+eidx] * (acc + bias[n])
// EPI 2: Cf[m,n] += wgt[m*8+eidx] * (acc + bias[n])
template<int EPI>
__global__ __launch_bounds__(256)
void gemm_bt(const unsigned short* __restrict__ A,
             const unsigned short* __restrict__ B,
             const float* __restrict__ bias,
             unsigned short* __restrict__ Cb, float* __restrict__ Cf,
             const float* __restrict__ wgt, int eidx,
             int M, int N, int K) {
  __shared__ alignas(16) unsigned short sA[128 * 64];
  __shared__ alignas(16) unsigned short sB[128 * 64];
  const int tid  = threadIdx.x;
  const int lane = tid & 63;
  const int wid  = tid >> 6;
  const int wr   = wid >> 1;
  const int wc   = wid & 1;
  const int bm = blockIdx.y * 128;
  const int bn = blockIdx.x * 128;

  const unsigned short* Ab = A + (size_t)bm * K;
  const unsigned short* Bb = B + (size_t)bn * K;

  const int srow  = wid * 8 + (lane >> 3);   // + it*32
  const int scol  = (lane & 7) * 8;
  const int sldsb = wid * 1024 + lane * 16;  // + it*4096 (bytes)

  f32x4 acc[4][4] = {};

  for (int k0 = 0; k0 < K; k0 += 64) {
    __syncthreads();
#pragma unroll
    for (int it = 0; it < 4; ++it) {
      const unsigned short* ga = Ab + (size_t)(it * 32 + srow) * K + (k0 + scol);
      const unsigned short* gb = Bb + (size_t)(it * 32 + srow) * K + (k0 + scol);
      __builtin_amdgcn_global_load_lds((const AS1 void*)ga,
          (AS3 void*)((char*)sA + it * 4096 + sldsb), 16, 0, 0);
      __builtin_amdgcn_global_load_lds((const AS1 void*)gb,
          (AS3 void*)((char*)sB + it * 4096 + sldsb), 16, 0, 0);
    }
    __syncthreads();

    short8 af[2][4], bfr[2][4];
#pragma unroll
    for (int kk = 0; kk < 2; ++kk) {
      const int kc = kk * 32 + (lane >> 4) * 8;
#pragma unroll
      for (int m = 0; m < 4; ++m)
        af[kk][m] = *(const short8*)&sA[(wr * 64 + m * 16 + (lane & 15)) * 64 + kc];
#pragma unroll
      for (int n = 0; n < 4; ++n)
        bfr[kk][n] = *(const short8*)&sB[(wc * 64 + n * 16 + (lane & 15)) * 64 + kc];
    }
#pragma unroll
    for (int kk = 0; kk < 2; ++kk)
#pragma unroll
      for (int m = 0; m < 4; ++m)
#pragma unroll
        for (int n = 0; n < 4; ++n)
          acc[m][n] = __builtin_amdgcn_mfma_f32_16x16x32_bf16(
              __builtin_bit_cast(bf16x8, af[kk][m]),
              __builtin_bit_cast(bf16x8, bfr[kk][n]), acc[m][n], 0, 0, 0);
  }

  // epilogue: C/D layout col=lane&15, row=(lane>>4)*4+reg  [m89-verified]
  const int rbase = bm + wr * 64 + ((lane >> 4) << 2);
  const int cbase = bn + wc * 64 + (lane & 15);
  float wv[4][4];
  if (EPI != 0) {
#pragma unroll
    for (int m = 0; m < 4; ++m)
#pragma unroll
      for (int r = 0; r < 4; ++r)
        wv[m][r] = wgt[(size_t)(rbase + m * 16 + r) * 8 + eidx];
  }
#pragma unroll
  for (int m = 0; m < 4; ++m) {
#pragma unroll
    for (int n = 0; n < 4; ++n) {
      const int col = cbase + n * 16;
      const float bv = bias[col];
#pragma unroll
      for (int r = 0; r < 4; ++r) {
        const int row = rbase + m * 16 + r;
        float v = acc[m][n][r] + bv;
        if (EPI == 0) {
          float g = 0.5f * v * (1.0f + erff(v * 0.70710678118654752f));
          Cb[(size_t)row * N + col] = f2bf(g);
        } else if (EPI == 1) {
          Cf[(size_t)row * N + col] = wv[m][r] * v;
        } else {
          Cf[(size_t)row * N + col] += wv[m][r] * v;
        }
      }
    }
  }
}

// ---------- gate logits (K=H dot with 8 experts) + softmax, 1 block/token ----------
__global__ void gate_softmax(const unsigned short* __restrict__ g2,
                             const unsigned short* __restrict__ W3,
                             const float* __restrict__ b3,
                             float* __restrict__ wout, int H) {
  const int m = blockIdx.x;
  const int lane = threadIdx.x & 63;
  const int wid  = threadIdx.x >> 6;
  float acc[8] = {0.f, 0.f, 0.f, 0.f, 0.f, 0.f, 0.f, 0.f};
  const unsigned short* grow = g2 + (size_t)m * H;
  for (int k = threadIdx.x * 8; k < H; k += 256 * 8) {
    short8 gv = *(const short8*)(grow + k);
    float gf[8];
#pragma unroll
    for (int j = 0; j < 8; ++j) gf[j] = bf2f((unsigned short)gv[j]);
#pragma unroll
    for (int e = 0; e < 8; ++e) {
      short8 wvv = *(const short8*)(W3 + (size_t)e * H + k);
#pragma unroll
      for (int j = 0; j < 8; ++j) acc[e] += gf[j] * bf2f((unsigned short)wvv[j]);
    }
  }
#pragma unroll
  for (int e = 0; e < 8; ++e)
#pragma unroll
    for (int off = 32; off > 0; off >>= 1) acc[e] += __shfl_down(acc[e], off);
  __shared__ float red[4][8];
  if (lane == 0) {
#pragma unroll
    for (int e = 0; e < 8; ++e) red[wid][e] = acc[e];
  }
  __syncthreads();
  if (threadIdx.x == 0) {
    float l[8], mx = -1e30f, s = 0.f;
#pragma unroll
    for (int e = 0; e < 8; ++e) {
      l[e] = red[0][e] + red[1][e] + red[2][e] + red[3][e] + b3[e];
      mx = fmaxf(mx, l[e]);
    }
#pragma unroll
    for (int e = 0; e < 8; ++e) { l[e] = expf(l[e] - mx); s += l[e]; }
    const float inv = 1.f / s;
#pragma unroll
    for (int e = 0; e < 8; ++e) wout[(size_t)m * 8 + e] = l[e] * inv;
  }
}

extern "C" void kernel_launch(void* const* d_in, const int* in_sizes, int n_in,
                              void* d_out, int out_size, void* d_ws, size_t ws_size,
                              hipStream_t stream) {
  const float* x   = (const float*)d_in[0];
  const float* gW1 = (const float*)d_in[1];
  const float* gb1 = (const float*)d_in[2];
  const float* gW2 = (const float*)d_in[3];
  const float* gb2 = (const float*)d_in[4];
  const float* gW3 = (const float*)d_in[5];
  const float* gb3 = (const float*)d_in[6];
  const float* eW1 = (const float*)d_in[7];
  const float* eb1 = (const float*)d_in[8];
  const float* eW2 = (const float*)d_in[9];
  const float* eb2 = (const float*)d_in[10];

  const int M = 4096, D = 1024, H = 4096, E = 8;

  float* outP = (float*)d_out;              // [M, D]
  float* wP   = outP + (size_t)M * D;       // [M, E] softmax weights

  char* ws = (char*)d_ws;
  size_t off = 0;
  auto alloc = [&](size_t bytes) -> void* {
    void* p = ws + off;
    off += (bytes + 255) & ~(size_t)255;
    return p;
  };
  unsigned short* xb   = (unsigned short*)alloc((size_t)M * D * 2);
  unsigned short* gW1b = (unsigned short*)alloc((size_t)H * D * 2);
  unsigned short* gW2b = (unsigned short*)alloc((size_t)H * H * 2);
  unsigned short* gW3b = (unsigned short*)alloc((size_t)E * H * 2);
  unsigned short* eW1b = (unsigned short*)alloc((size_t)E * H * D * 2);
  unsigned short* eW2b = (unsigned short*)alloc((size_t)E * D * H * 2);
  unsigned short* g1b  = (unsigned short*)alloc((size_t)M * H * 2);
  unsigned short* g2b  = (unsigned short*)alloc((size_t)M * H * 2);
  unsigned short* hb   = (unsigned short*)alloc((size_t)M * H * 2);

  auto cvt = [&](const float* src, unsigned short* dst, size_t n) {
    size_t n4 = n >> 2;
    size_t b = (n4 + 255) >> 8;
    if (b > 2048) b = 2048;
    cvt_f32_bf16<<<dim3((unsigned)b), dim3(256), 0, stream>>>(
        (const float4*)src, (ushort4v*)dst, n4);
  };
  cvt(x,   xb,   (size_t)M * D);
  cvt(gW1, gW1b, (size_t)H * D);
  cvt(gW2, gW2b, (size_t)H * H);
  cvt(gW3, gW3b, (size_t)E * H);
  cvt(eW1, eW1b, (size_t)E * H * D);
  cvt(eW2, eW2b, (size_t)E * D * H);

  // gate layer 1: g1 = gelu(x @ gW1^T + gb1)   [M,H], K=D
  gemm_bt<0><<<dim3(H / 128, M / 128), dim3(256), 0, stream>>>(
      xb, gW1b, gb1, g1b, nullptr, nullptr, 0, M, H, D);
  // gate layer 2: g2 = gelu(g1 @ gW2^T + gb2)  [M,H], K=H
  gemm_bt<0><<<dim3(H / 128, M / 128), dim3(256), 0, stream>>>(
      g1b, gW2b, gb2, g2b, nullptr, nullptr, 0, M, H, H);
  // logits + softmax -> wP [M,8]
  gate_softmax<<<dim3(M), dim3(256), 0, stream>>>(g2b, gW3b, gb3, wP, H);

  // experts: h = gelu(x @ eW1[e]^T + eb1[e]); out (+)= w[:,e]*(h @ eW2[e]^T + eb2[e])
  for (int e = 0; e < E; ++e) {
    gemm_bt<0><<<dim3(H / 128, M / 128), dim3(256), 0, stream>>>(
        xb, eW1b + (size_t)e * H * D, eb1 + (size_t)e * H, hb,
        nullptr, nullptr, 0, M, H, D);
    if (e == 0) {
      gemm_bt<1><<<dim3(D / 128, M / 128), dim3(256), 0, stream>>>(
          hb, eW2b + (size_t)e * D * H, eb2 + (size_t)e * D, nullptr,
          outP, wP, e, M, D, H);
    } else {
      gemm_bt<2><<<dim3(D / 128, M / 128), dim3(256), 0, stream>>>(
          hb, eW2b + (size_t)e * D * H, eb2 + (size_t)e * D, nullptr,
          outP, wP, e, M, D, H);
    }
  }
}

// Round 2
// 1923.354 us; speedup vs baseline: 1.0214x; 1.0214x over previous
//
#include <hip/hip_runtime.h>
#include <hip/hip_bf16.h>
#include <math.h>

typedef __attribute__((ext_vector_type(8))) __bf16 bf16x8;
typedef __attribute__((ext_vector_type(8))) short short8;
typedef __attribute__((ext_vector_type(4))) float f32x4;
typedef __attribute__((ext_vector_type(4))) unsigned short ushort4v;

#define AS1 __attribute__((address_space(1)))
#define AS3 __attribute__((address_space(3)))

__device__ __forceinline__ unsigned short f2bf(float f) {
  __hip_bfloat16 h = __float2bfloat16(f);
  return __builtin_bit_cast(unsigned short, h);
}
__device__ __forceinline__ float bf2f(unsigned short s) {
  unsigned int u = ((unsigned int)s) << 16;
  return __builtin_bit_cast(float, u);
}

// ---------- fp32 -> bf16 conversion ----------
__global__ void cvt_f32_bf16(const float4* __restrict__ in,
                             ushort4v* __restrict__ out, size_t n4) {
  size_t i = (size_t)blockIdx.x * blockDim.x + threadIdx.x;
  size_t stride = (size_t)gridDim.x * blockDim.x;
  for (; i < n4; i += stride) {
    float4 v = in[i];
    ushort4v o = { f2bf(v.x), f2bf(v.y), f2bf(v.z), f2bf(v.w) };
    out[i] = o;
  }
}

#define MFMA16(a, b, c) __builtin_amdgcn_mfma_f32_16x16x32_bf16( \
    __builtin_bit_cast(bf16x8, a), __builtin_bit_cast(bf16x8, b), c, 0, 0, 0)

// ---------- 256x256 bf16 GEMM: C = A[M,K] * B[N,K]^T (+bias) ----------
// 8 waves (2M x 4N), per-wave 128x64 out, BK=64, 2 LDS buffers (128KB),
// 1-iteration stage lead with counted vmcnt(8), T2 XOR swizzle, T5 setprio.
// EPI 0: Cb = bf16(gelu(v))          (v = acc + bias[col])
// EPI 1: Cf  = wgt[row*8+eidx] * v
// EPI 2: Cf += wgt[row*8+eidx] * v
// EPI 3: Cf[z*cZ + ...] = wgt[row*8+z] * v   (grouped partials)
template<int EPI>
__global__ __launch_bounds__(512, 2)
void gemm256(const unsigned short* __restrict__ A, size_t aZ,
             const unsigned short* __restrict__ B, size_t bZ,
             const float* __restrict__ bias, size_t biasZ,
             unsigned short* __restrict__ Cb, float* __restrict__ Cf, size_t cZ,
             const float* __restrict__ wgt, int eidx,
             int M, int N, int K) {
  __shared__ alignas(16) unsigned short sm[65536];  // 2 bufs x (A 16384 + B 16384)
  const int tid  = threadIdx.x;
  const int lane = tid & 63;
  const int wid  = tid >> 6;
  const int wr   = wid >> 2;   // 0..1
  const int wc   = wid & 3;    // 0..3
  const int z    = blockIdx.z;

  // XCD-aware swizzle (all grids here have gx*gy % 8 == 0)
  const int gx = gridDim.x;
  const int nwg = gx * gridDim.y;
  const int lin = blockIdx.y * gx + blockIdx.x;
  const int cpx = nwg >> 3;
  const int swb = (lin & 7) * cpx + (lin >> 3);
  const int bm = (swb / gx) * 256;
  const int bn = (swb % gx) * 256;

  const unsigned short* Ab = A + z * aZ + (size_t)bm * K;
  const unsigned short* Bb = B + z * bZ + (size_t)bn * K;

  // staging: 4 A-loads + 4 B-loads per thread per K-tile (16B each).
  // LDS dest linear (phys slot p = i*512+tid); global source inverse-swizzled.
  const unsigned short* ga[4];
  const unsigned short* gb[4];
  int ldsA[4], ldsB[4];
#pragma unroll
  for (int i = 0; i < 4; ++i) {
    const int p   = i * 512 + tid;
    const int row = p >> 3;                 // 0..255
    const int q   = (p & 7) ^ (row & 7);    // logical 8-elem k-chunk at this slot
    ga[i] = Ab + (size_t)row * K + q * 8;
    gb[i] = Bb + (size_t)row * K + q * 8;
    ldsA[i] = p * 8;
    ldsB[i] = 16384 + p * 8;
  }

  auto stage = [&](int buf) {
    unsigned short* base = &sm[buf * 32768];
#pragma unroll
    for (int i = 0; i < 4; ++i) {
      __builtin_amdgcn_global_load_lds((const AS1 void*)ga[i],
          (AS3 void*)(base + ldsA[i]), 16, 0, 0);
      __builtin_amdgcn_global_load_lds((const AS1 void*)gb[i],
          (AS3 void*)(base + ldsB[i]), 16, 0, 0);
      ga[i] += 64; gb[i] += 64;
    }
  };

  f32x4 acc[8][4] = {};
  const int swzr    = (lane & 7) << 3;                  // row&7 == lane&7 for all frags
  const int aoffb   = (wr * 128 + (lane & 15)) * 64;
  const int boffb   = (wc * 64 + (lane & 15)) * 64 + 16384;
  const int kchunk0 = (lane >> 4) * 8;

  stage(0);
  const int NT = K >> 6;
  for (int t = 0; t < NT; ++t) {
    const int b = t & 1;
    if (t + 1 < NT) {
      stage(b ^ 1);
      asm volatile("s_waitcnt vmcnt(8)" ::: "memory");   // tile t landed (mine)
    } else {
      asm volatile("s_waitcnt vmcnt(0)" ::: "memory");
    }
    __builtin_amdgcn_s_barrier();                        // all waves' tile t visible
    asm volatile("" ::: "memory");

    const unsigned short* sbuf = &sm[b * 32768];
#pragma unroll
    for (int kk = 0; kk < 2; ++kk) {
      const int kx = ((kk * 32) + kchunk0) ^ swzr;
      short8 af[8], bfr[4];
#pragma unroll
      for (int mf = 0; mf < 8; ++mf)
        af[mf] = *(const short8*)&sbuf[aoffb + mf * 1024 + kx];
#pragma unroll
      for (int nf = 0; nf < 4; ++nf)
        bfr[nf] = *(const short8*)&sbuf[boffb + nf * 1024 + kx];
      __builtin_amdgcn_s_setprio(1);
#pragma unroll
      for (int mf = 0; mf < 8; ++mf)
#pragma unroll
        for (int nf = 0; nf < 4; ++nf)
          acc[mf][nf] = MFMA16(af[mf], bfr[nf], acc[mf][nf]);
      __builtin_amdgcn_s_setprio(0);
    }
    asm volatile("" ::: "memory");
    __builtin_amdgcn_s_barrier();                        // reads done; buf reusable
    asm volatile("" ::: "memory");
  }

  // epilogue: C/D layout col=lane&15, row=(lane>>4)*4+reg
  const int rbase = bm + wr * 128 + ((lane >> 4) << 2);
  const int cbase = bn + wc * 64 + (lane & 15);
  float wv[8][4];
  if (EPI != 0) {
    const int ei = (EPI == 3) ? z : eidx;
#pragma unroll
    for (int mf = 0; mf < 8; ++mf)
#pragma unroll
      for (int r = 0; r < 4; ++r)
        wv[mf][r] = wgt[(size_t)(rbase + mf * 16 + r) * 8 + ei];
  }
#pragma unroll
  for (int mf = 0; mf < 8; ++mf) {
#pragma unroll
    for (int nf = 0; nf < 4; ++nf) {
      const int col = cbase + nf * 16;
      const float bv = bias[z * biasZ + col];
#pragma unroll
      for (int r = 0; r < 4; ++r) {
        const int row = rbase + mf * 16 + r;
        const float v = acc[mf][nf][r] + bv;
        if (EPI == 0) {
          float g = 0.5f * v * (1.0f + erff(v * 0.70710678118654752f));
          Cb[z * cZ + (size_t)row * N + col] = f2bf(g);
        } else if (EPI == 1) {
          Cf[(size_t)row * N + col] = wv[mf][r] * v;
        } else if (EPI == 2) {
          Cf[(size_t)row * N + col] += wv[mf][r] * v;
        } else {
          Cf[z * cZ + (size_t)row * N + col] = wv[mf][r] * v;
        }
      }
    }
  }
}

// ---------- gate logits (E=8) + softmax, 1 block/token ----------
__global__ void gate_softmax(const unsigned short* __restrict__ g2,
                             const unsigned short* __restrict__ W3,
                             const float* __restrict__ b3,
                             float* __restrict__ wout, int H) {
  const int m = blockIdx.x;
  const int lane = threadIdx.x & 63;
  const int wid  = threadIdx.x >> 6;
  float acc[8] = {0.f, 0.f, 0.f, 0.f, 0.f, 0.f, 0.f, 0.f};
  const unsigned short* grow = g2 + (size_t)m * H;
  for (int k = threadIdx.x * 8; k < H; k += 256 * 8) {
    short8 gv = *(const short8*)(grow + k);
    float gf[8];
#pragma unroll
    for (int j = 0; j < 8; ++j) gf[j] = bf2f((unsigned short)gv[j]);
#pragma unroll
    for (int e = 0; e < 8; ++e) {
      short8 wvv = *(const short8*)(W3 + (size_t)e * H + k);
#pragma unroll
      for (int j = 0; j < 8; ++j) acc[e] += gf[j] * bf2f((unsigned short)wvv[j]);
    }
  }
#pragma unroll
  for (int e = 0; e < 8; ++e)
#pragma unroll
    for (int off = 32; off > 0; off >>= 1) acc[e] += __shfl_down(acc[e], off);
  __shared__ float red[4][8];
  if (lane == 0) {
#pragma unroll
    for (int e = 0; e < 8; ++e) red[wid][e] = acc[e];
  }
  __syncthreads();
  if (threadIdx.x == 0) {
    float l[8], mx = -1e30f, s = 0.f;
#pragma unroll
    for (int e = 0; e < 8; ++e) {
      l[e] = red[0][e] + red[1][e] + red[2][e] + red[3][e] + b3[e];
      mx = fmaxf(mx, l[e]);
    }
#pragma unroll
    for (int e = 0; e < 8; ++e) { l[e] = expf(l[e] - mx); s += l[e]; }
    const float inv = 1.f / s;
#pragma unroll
    for (int e = 0; e < 8; ++e) wout[(size_t)m * 8 + e] = l[e] * inv;
  }
}

// ---------- sum of 8 expert partials ----------
__global__ void reduce8(const float4* __restrict__ in, float4* __restrict__ out,
                        int n4) {
  int i = blockIdx.x * 256 + threadIdx.x;
  const int stride = gridDim.x * 256;
  for (; i < n4; i += stride) {
    float4 s = in[i];
#pragma unroll
    for (int zz = 1; zz < 8; ++zz) {
      float4 v = in[(size_t)zz * n4 + i];
      s.x += v.x; s.y += v.y; s.z += v.z; s.w += v.w;
    }
    out[i] = s;
  }
}

extern "C" void kernel_launch(void* const* d_in, const int* in_sizes, int n_in,
                              void* d_out, int out_size, void* d_ws, size_t ws_size,
                              hipStream_t stream) {
  const float* x   = (const float*)d_in[0];
  const float* gW1 = (const float*)d_in[1];
  const float* gb1 = (const float*)d_in[2];
  const float* gW2 = (const float*)d_in[3];
  const float* gb2 = (const float*)d_in[4];
  const float* gW3 = (const float*)d_in[5];
  const float* gb3 = (const float*)d_in[6];
  const float* eW1 = (const float*)d_in[7];
  const float* eb1 = (const float*)d_in[8];
  const float* eW2 = (const float*)d_in[9];
  const float* eb2 = (const float*)d_in[10];

  const int M = 4096, D = 1024, H = 4096, E = 8;

  float* outP = (float*)d_out;              // [M, D]
  float* wP   = outP + (size_t)M * D;       // [M, E]

  char* ws = (char*)d_ws;
  size_t off = 0;
  auto alloc = [&](size_t bytes) -> void* {
    void* p = ws + off;
    off += (bytes + 255) & ~(size_t)255;
    return p;
  };
  unsigned short* xb   = (unsigned short*)alloc((size_t)M * D * 2);
  unsigned short* gW1b = (unsigned short*)alloc((size_t)H * D * 2);
  unsigned short* gW2b = (unsigned short*)alloc((size_t)H * H * 2);
  unsigned short* gW3b = (unsigned short*)alloc((size_t)E * H * 2);
  unsigned short* eW1b = (unsigned short*)alloc((size_t)E * H * D * 2);
  unsigned short* eW2b = (unsigned short*)alloc((size_t)E * D * H * 2);
  unsigned short* g1b  = (unsigned short*)alloc((size_t)M * H * 2);
  unsigned short* g2b  = (unsigned short*)alloc((size_t)M * H * 2);
  const size_t base_off = off;

  // tier sizing
  const size_t hall_b = (size_t)E * M * H * 2;   // 256 MB
  const size_t eo_b   = (size_t)E * M * D * 4;   // 128 MB
  const int tier = (ws_size >= base_off + hall_b + eo_b) ? 1
                 : (ws_size >= base_off + hall_b)        ? 2
                                                         : 3;

  auto cvt = [&](const float* src, unsigned short* dst, size_t n) {
    size_t n4 = n >> 2;
    size_t b = (n4 + 255) >> 8;
    if (b > 2048) b = 2048;
    cvt_f32_bf16<<<dim3((unsigned)b), dim3(256), 0, stream>>>(
        (const float4*)src, (ushort4v*)dst, n4);
  };
  cvt(x,   xb,   (size_t)M * D);
  cvt(gW1, gW1b, (size_t)H * D);
  cvt(gW2, gW2b, (size_t)H * H);
  cvt(gW3, gW3b, (size_t)E * H);
  cvt(eW1, eW1b, (size_t)E * H * D);
  cvt(eW2, eW2b, (size_t)E * D * H);

  // gate1: g1 = gelu(x @ gW1^T + gb1)   [M,H], K=D
  gemm256<0><<<dim3(H / 256, M / 256, 1), dim3(512), 0, stream>>>(
      xb, 0, gW1b, 0, gb1, 0, g1b, nullptr, 0, nullptr, 0, M, H, D);
  // gate2: g2 = gelu(g1 @ gW2^T + gb2)  [M,H], K=H
  gemm256<0><<<dim3(H / 256, M / 256, 1), dim3(512), 0, stream>>>(
      g1b, 0, gW2b, 0, gb2, 0, g2b, nullptr, 0, nullptr, 0, M, H, H);
  // softmax weights
  gate_softmax<<<dim3(M), dim3(256), 0, stream>>>(g2b, gW3b, gb3, wP, H);

  if (tier <= 2) {
    unsigned short* h_all = (unsigned short*)alloc(hall_b);
    // expert layer 1, all experts grouped: h_all[e] = gelu(x @ eW1[e]^T + eb1[e])
    gemm256<0><<<dim3(H / 256, M / 256, E), dim3(512), 0, stream>>>(
        xb, 0, eW1b, (size_t)H * D, eb1, H, h_all, nullptr, (size_t)M * H,
        nullptr, 0, M, H, D);
    if (tier == 1) {
      float* eo_all = (float*)alloc(eo_b);
      // expert layer 2 grouped -> weighted partials
      gemm256<3><<<dim3(D / 256, M / 256, E), dim3(512), 0, stream>>>(
          h_all, (size_t)M * H, eW2b, (size_t)D * H, eb2, D,
          nullptr, eo_all, (size_t)M * D, wP, 0, M, D, H);
      reduce8<<<dim3(2048), dim3(256), 0, stream>>>(
          (const float4*)eo_all, (float4*)outP, (int)((size_t)M * D / 4));
    } else {
      for (int e = 0; e < E; ++e) {
        if (e == 0)
          gemm256<1><<<dim3(D / 256, M / 256, 1), dim3(512), 0, stream>>>(
              h_all + (size_t)e * M * H, 0, eW2b + (size_t)e * D * H, 0,
              eb2 + (size_t)e * D, 0, nullptr, outP, 0, wP, e, M, D, H);
        else
          gemm256<2><<<dim3(D / 256, M / 256, 1), dim3(512), 0, stream>>>(
              h_all + (size_t)e * M * H, 0, eW2b + (size_t)e * D * H, 0,
              eb2 + (size_t)e * D, 0, nullptr, outP, 0, wP, e, M, D, H);
      }
    }
  } else {
    // tier 3: sequential, h aliases g1b (free after softmax)
    unsigned short* hb = g1b;
    for (int e = 0; e < E; ++e) {
      gemm256<0><<<dim3(H / 256, M / 256, 1), dim3(512), 0, stream>>>(
          xb, 0, eW1b + (size_t)e * H * D, 0, eb1 + (size_t)e * H, 0,
          hb, nullptr, 0, nullptr, 0, M, H, D);
      if (e == 0)
        gemm256<1><<<dim3(D / 256, M / 256, 1), dim3(512), 0, stream>>>(
            hb, 0, eW2b + (size_t)e * D * H, 0, eb2 + (size_t)e * D, 0,
            nullptr, outP, 0, wP, e, M, D, H);
      else
        gemm256<2><<<dim3(D / 256, M / 256, 1), dim3(512), 0, stream>>>(
            hb, 0, eW2b + (size_t)e * D * H, 0, eb2 + (size_t)e * D, 0,
            nullptr, outP, 0, wP, e, M, D, H);
    }
  }
}